// Round 1
// baseline (4337.962 us; speedup 1.0000x reference)
//
#include <hip/hip_runtime.h>
#include <math.h>

// Problem constants (B,S,D,K,DF,H,DFF = 2,512,512,8,64,8,2048)
#define BB 2
#define SS 512
#define DD 512
#define KK8 8
#define DF 64
#define HH 8
#define DFF 2048
#define DH 64
#define CS 64

#define TILE 64
#define BK 16

__device__ __forceinline__ float gelu_exact(float v) {
    return 0.5f * v * (1.0f + erff(v * 0.70710678118654752f));
}

// Generic tiled fp32 GEMM: C = act(scale*(A@B or A@B^T) + bias) + resid
// Block 256 threads, 64x64 tile, per-thread 4x4. All dims multiples of the
// tile in this problem, so no bounds checks.
// Batched via blockIdx.z: offset = (z/batchH)*SB + (z%batchH)*SH per operand.
template<bool TRANSB>
__global__ __launch_bounds__(256)
void gemm_k(const float* __restrict__ Ab, const float* __restrict__ Bb,
            const float* __restrict__ bias, const float* __restrict__ resid,
            float* __restrict__ Cb,
            int K, int lda, int ldb, int ldc,
            int batchH,
            long aSB, long aSH, long bSB, long bSH, long cSB, long cSH,
            int act, float scale)
{
    __shared__ float As[BK][TILE + 1];
    __shared__ float Bs[BK][TILE + 1];
    const int z = blockIdx.z;
    const int zb = z / batchH, zh = z % batchH;
    const float* A = Ab + (long)zb * aSB + (long)zh * aSH;
    const float* B = Bb + (long)zb * bSB + (long)zh * bSH;
    float* C = Cb + (long)zb * cSB + (long)zh * cSH;
    const int tid = threadIdx.x;
    const int tx = tid & 15, ty = tid >> 4;
    const int row0 = blockIdx.y * TILE;
    const int col0 = blockIdx.x * TILE;
    float acc[4][4] = {};
    for (int k0 = 0; k0 < K; k0 += BK) {
        {   // A tile: As[kk][m] = A[row0+m][k0+kk]
            const int kk = tid & 15;
            const int m0 = tid >> 4;
            #pragma unroll
            for (int p = 0; p < 4; ++p) {
                const int m = m0 + p * 16;
                As[kk][m] = A[(long)(row0 + m) * lda + (k0 + kk)];
            }
        }
        if (!TRANSB) {  // Bs[kk][n] = B[k0+kk][col0+n]
            const int n = tid & 63;
            const int kq = tid >> 6;
            #pragma unroll
            for (int p = 0; p < 4; ++p) {
                const int kk = kq + p * 4;
                Bs[kk][n] = B[(long)(k0 + kk) * ldb + (col0 + n)];
            }
        } else {        // Bs[kk][n] = B[col0+n][k0+kk]
            const int kk = tid & 15;
            const int n0 = tid >> 4;
            #pragma unroll
            for (int p = 0; p < 4; ++p) {
                const int n = n0 + p * 16;
                Bs[kk][n] = B[(long)(col0 + n) * ldb + (k0 + kk)];
            }
        }
        __syncthreads();
        #pragma unroll
        for (int kk = 0; kk < BK; ++kk) {
            float a[4], b[4];
            #pragma unroll
            for (int i = 0; i < 4; ++i) a[i] = As[kk][ty * 4 + i];
            #pragma unroll
            for (int j = 0; j < 4; ++j) b[j] = Bs[kk][tx * 4 + j];
            #pragma unroll
            for (int i = 0; i < 4; ++i)
                #pragma unroll
                for (int j = 0; j < 4; ++j)
                    acc[i][j] = fmaf(a[i], b[j], acc[i][j]);
        }
        __syncthreads();
    }
    #pragma unroll
    for (int i = 0; i < 4; ++i) {
        const int r = row0 + ty * 4 + i;
        #pragma unroll
        for (int j = 0; j < 4; ++j) {
            const int c = col0 + tx * 4 + j;
            float v = acc[i][j] * scale;
            if (bias)  v += bias[c];
            if (act == 1) v = gelu_exact(v);
            if (resid) v += resid[(long)r * ldc + c];
            C[(long)r * ldc + c] = v;
        }
    }
}

// LayerNorm over last dim (2048), in-place. One block (256 thr) per row.
__global__ __launch_bounds__(256)
void ln_k(float* __restrict__ h, const float* __restrict__ g,
          const float* __restrict__ b)
{
    const long row = blockIdx.x;
    float* r = h + row * (long)DFF;
    const int tid = threadIdx.x;
    float vals[8];
    float s = 0.f, sq = 0.f;
    #pragma unroll
    for (int e = 0; e < 8; ++e) {
        float v = r[tid + e * 256];
        vals[e] = v; s += v; sq += v * v;
    }
    __shared__ float rs[256], rq[256];
    rs[tid] = s; rq[tid] = sq; __syncthreads();
    for (int st = 128; st > 0; st >>= 1) {
        if (tid < st) { rs[tid] += rs[tid + st]; rq[tid] += rq[tid + st]; }
        __syncthreads();
    }
    const float mean = rs[0] * (1.f / DFF);
    const float var  = rq[0] * (1.f / DFF) - mean * mean;
    const float inv  = rsqrtf(var + 1e-5f);
    #pragma unroll
    for (int e = 0; e < 8; ++e) {
        const int c = tid + e * 256;
        r[c] = (vals[e] - mean) * inv * g[c] + b[c];
    }
}

// xa[b,j,kl] = sum_d x[b,j,d] * A[b,j,d,kl].  One block (256 thr) per (b,j).
__global__ __launch_bounds__(256)
void xa_k(const float* __restrict__ x, const float* __restrict__ Abuf,
          float* __restrict__ xa)
{
    const int bj = blockIdx.x;
    const int tid = threadIdx.x;
    const int n = tid & 63, dd = tid >> 6;
    const float* Aj = Abuf + (long)bj * 512 * 64;
    const float* xr = x + (long)bj * 512;
    float acc = 0.f;
    for (int d = dd; d < 512; d += 4)
        acc = fmaf(xr[d], Aj[(long)d * 64 + n], acc);
    __shared__ float red[4][64];
    red[dd][n] = acc; __syncthreads();
    if (dd == 0)
        xa[(long)bj * 64 + n] = red[0][n] + red[1][n] + red[2][n] + red[3][n];
}

// Fused: lie tile GEMM (64 i's x 64 kl, K=512) -> M = -(lie) -> 6-term Taylor
// matexp -> Gamma[b,i,j,kl].  Grid: (i_tile=8, j=512, b=2), 256 threads.
__global__ __launch_bounds__(256)
void liegamma_k(const float* __restrict__ x, const float* __restrict__ Abuf,
                const float* __restrict__ xa, float* __restrict__ Gamma)
{
    __shared__ float As[BK][TILE + 1];
    __shared__ float Bs[BK][TILE + 1];
    __shared__ float Ml[64][65];
    const int b = blockIdx.z;
    const int j = blockIdx.y;
    const int i0 = blockIdx.x * 64;
    const float* Ar = x + (long)b * 512 * 512;
    const float* Br = Abuf + ((long)(b * 512 + j)) * 512 * 64;  // [d,kl]
    const int tid = threadIdx.x;
    const int tx = tid & 15, ty = tid >> 4;
    float acc[4][4] = {};
    for (int k0 = 0; k0 < 512; k0 += BK) {
        {
            const int kk = tid & 15;
            const int m0 = tid >> 4;
            #pragma unroll
            for (int p = 0; p < 4; ++p) {
                const int m = m0 + p * 16;
                As[kk][m] = Ar[(long)(i0 + m) * 512 + (k0 + kk)];
            }
        }
        {
            const int n = tid & 63;
            const int kq = tid >> 6;
            #pragma unroll
            for (int p = 0; p < 4; ++p) {
                const int kk = kq + p * 4;
                Bs[kk][n] = Br[(long)(k0 + kk) * 64 + n];
            }
        }
        __syncthreads();
        #pragma unroll
        for (int kk = 0; kk < BK; ++kk) {
            float a[4], bb[4];
            #pragma unroll
            for (int i = 0; i < 4; ++i) a[i] = As[kk][ty * 4 + i];
            #pragma unroll
            for (int jj = 0; jj < 4; ++jj) bb[jj] = Bs[kk][tx * 4 + jj];
            #pragma unroll
            for (int i = 0; i < 4; ++i)
                #pragma unroll
                for (int jj = 0; jj < 4; ++jj)
                    acc[i][jj] = fmaf(a[i], bb[jj], acc[i][jj]);
        }
        __syncthreads();
    }
    // M = xa[b,j,:] - acc  (i.e. -lie)
    const float* xar = xa + ((long)(b * 512 + j)) * 64;
    #pragma unroll
    for (int i = 0; i < 4; ++i)
        #pragma unroll
        for (int jj = 0; jj < 4; ++jj)
            Ml[ty * 4 + i][tx * 4 + jj] = xar[tx * 4 + jj] - acc[i][jj];
    __syncthreads();
    // matexp: 8 threads per 8x8 matrix, 32 matrices per pass, 2 passes.
    const int r = tid & 7;
    const int mg = tid >> 3;
    #pragma unroll
    for (int pass = 0; pass < 2; ++pass) {
        const int mi = pass * 32 + mg;
        float P[8], res[8];
        #pragma unroll
        for (int c = 0; c < 8; ++c) { float iv = (c == r) ? 1.f : 0.f; P[c] = iv; res[c] = iv; }
        #pragma unroll
        for (int n = 1; n <= 6; ++n) {
            float tmp[8];
            const float invn = 1.f / (float)n;
            #pragma unroll
            for (int c = 0; c < 8; ++c) {
                float s = 0.f;
                #pragma unroll
                for (int l = 0; l < 8; ++l) s = fmaf(P[l], Ml[mi][l * 8 + c], s);
                tmp[c] = s * invn;
            }
            #pragma unroll
            for (int c = 0; c < 8; ++c) { P[c] = tmp[c]; res[c] += P[c]; }
        }
        float* outp = Gamma + (((long)(b * 512 + (i0 + mi)) * 512 + j)) * 64 + r * 8;
        #pragma unroll
        for (int c = 0; c < 8; ++c) outp[c] = res[c];
    }
}

// Softmax over last dim (512), in-place. One block (256 thr) per row.
__global__ __launch_bounds__(256)
void softmax_k(float* __restrict__ p)
{
    const long row = blockIdx.x;
    float* r = p + row * 512;
    const int tid = threadIdx.x;
    float v0 = r[tid], v1 = r[tid + 256];
    __shared__ float red[256];
    red[tid] = fmaxf(v0, v1); __syncthreads();
    for (int s = 128; s > 0; s >>= 1) {
        if (tid < s) red[tid] = fmaxf(red[tid], red[tid + s]);
        __syncthreads();
    }
    const float m = red[0]; __syncthreads();
    v0 = expf(v0 - m); v1 = expf(v1 - m);
    red[tid] = v0 + v1; __syncthreads();
    for (int s = 128; s > 0; s >>= 1) {
        if (tid < s) red[tid] += red[tid + s];
        __syncthreads();
    }
    const float inv = 1.f / red[0];
    r[tid] = v0 * inv; r[tid + 256] = v1 * inv;
}

// attn_avg[b,i,j] = mean_h attn[b,h,i,j]
__global__ __launch_bounds__(256)
void aavg_k(const float* __restrict__ attn, float* __restrict__ aavg)
{
    const long idx = (long)blockIdx.x * 256 + threadIdx.x;  // 524288 total
    const int b = (int)(idx >> 18);
    const long rem = idx & 262143;
    float s = 0.f;
    #pragma unroll
    for (int h = 0; h < HH; ++h)
        s += attn[(long)b * 2097152 + (long)h * 262144 + rem];
    aavg[idx] = s * 0.125f;
}

// u_t[b,i,k,c] = sum_j aavg[b,i,j] * sum_l Gamma[b,i,j,k,l] * uproj[b,j,l*64+c]
// One block (512 thr) per (b,i); j tiled by 8 through LDS.
__global__ __launch_bounds__(512)
void ut_k(const float* __restrict__ Gamma, const float* __restrict__ aavg,
          const float* __restrict__ uproj, float* __restrict__ ut)
{
    const int bi = blockIdx.x;               // b*512 + i
    const int b = bi >> 9;
    const int tid = threadIdx.x;
    const int k = tid >> 6, c = tid & 63;
    __shared__ float Gs[8][64];
    __shared__ float Us[8][512];
    __shared__ float as_[8];
    const float* Grow = Gamma + (long)bi * 512 * 64;  // [j][64]
    const float* arow = aavg + (long)bi * 512;
    const float* ub   = uproj + (long)b * 512 * 512;  // [j][512]
    float acc = 0.f;
    for (int j0 = 0; j0 < 512; j0 += 8) {
        {
            const int jj = tid >> 6, kl = tid & 63;
            Gs[jj][kl] = Grow[(long)(j0 + jj) * 64 + kl];
        }
        #pragma unroll
        for (int rr = 0; rr < 8; ++rr)
            Us[rr][tid] = ub[(long)(j0 + rr) * 512 + tid];
        if (tid < 8) as_[tid] = arow[j0 + tid];
        __syncthreads();
        #pragma unroll
        for (int jj = 0; jj < 8; ++jj) {
            float s = 0.f;
            #pragma unroll
            for (int l = 0; l < 8; ++l)
                s = fmaf(Gs[jj][k * 8 + l], Us[jj][l * 64 + c], s);
            acc = fmaf(as_[jj], s, acc);
        }
        __syncthreads();
    }
    ut[(long)bi * 512 + tid] = acc;   // tid == k*64 + c
}

extern "C" void kernel_launch(void* const* d_in, const int* in_sizes, int n_in,
                              void* d_out, int out_size, void* d_ws, size_t ws_size,
                              hipStream_t stream) {
    const float* x   = (const float*)d_in[0];
    const float* u   = (const float*)d_in[1];
    const float* Wq  = (const float*)d_in[2];  const float* bq  = (const float*)d_in[3];
    const float* Wk  = (const float*)d_in[4];  const float* bk  = (const float*)d_in[5];
    const float* Wv  = (const float*)d_in[6];  const float* bv  = (const float*)d_in[7];
    const float* Wo  = (const float*)d_in[8];  const float* bo  = (const float*)d_in[9];
    const float* Wfp = (const float*)d_in[10]; const float* bfp = (const float*)d_in[11];
    const float* Wfo = (const float*)d_in[12]; const float* bfo = (const float*)d_in[13];
    const float* Wc1 = (const float*)d_in[14]; const float* bc1 = (const float*)d_in[15];
    const float* gln = (const float*)d_in[16]; const float* bln = (const float*)d_in[17];
    const float* Wc2 = (const float*)d_in[18]; const float* bc2 = (const float*)d_in[19];

    float* ws = (float*)d_ws;
    // Persistent region (277 MB peak):
    float* h    = ws;                       // 2,097,152
    float* Abuf = ws + 2097152;             // 33,554,432
    float* Gm   = Abuf + 33554432;          // 33,554,432
    float* xa   = Gm + 33554432;            //    65,536
    // Attention-phase buffers alias the (dead after liegamma) A region:
    float* q    = Abuf;
    float* kb   = Abuf + 524288;
    float* v    = Abuf + 1048576;
    float* sc   = Abuf + 1572864;           // 4,194,304 (scores/attn)
    float* av   = Abuf + 5767168;           //   524,288 (attn_avg)
    float* ctx  = Abuf + 6291456;
    float* up   = Abuf + 6815744;           // u_proj
    float* ut   = Abuf + 7340032;
    float* xout = (float*)d_out;
    float* uout = xout + 524288;

    const dim3 blk(256);

    // 1) h_pre = gelu(x @ Wc1 + bc1)   [1024,2048]
    gemm_k<false><<<dim3(DFF / 64, 1024 / 64, 1), blk, 0, stream>>>(
        x, Wc1, bc1, nullptr, h, DD, DD, DFF, DFF,
        1, 0L, 0L, 0L, 0L, 0L, 0L, 1, 1.0f);
    // 2) h = LayerNorm(h_pre)
    ln_k<<<dim3(1024), blk, 0, stream>>>(h, gln, bln);
    // 3) A = h @ Wc2 + bc2   [1024, 32768]
    gemm_k<false><<<dim3(32768 / 64, 1024 / 64, 1), blk, 0, stream>>>(
        h, Wc2, bc2, nullptr, Abuf, DFF, DFF, 32768, 32768,
        1, 0L, 0L, 0L, 0L, 0L, 0L, 0, 1.0f);
    // 4) xa[b,j,kl]
    xa_k<<<dim3(1024), blk, 0, stream>>>(x, Abuf, xa);
    // 5) Gamma = matexp(-(x_i.A_j - xa_j))   (fused lie GEMM + Taylor)
    liegamma_k<<<dim3(8, 512, 2), blk, 0, stream>>>(x, Abuf, xa, Gm);
    // 6) q,k,v = x@W + b   [1024,512] each   (A region now dead -> reused)
    gemm_k<false><<<dim3(8, 16, 1), blk, 0, stream>>>(
        x, Wq, bq, nullptr, q, DD, DD, DD, DD, 1, 0L,0L,0L,0L,0L,0L, 0, 1.0f);
    gemm_k<false><<<dim3(8, 16, 1), blk, 0, stream>>>(
        x, Wk, bk, nullptr, kb, DD, DD, DD, DD, 1, 0L,0L,0L,0L,0L,0L, 0, 1.0f);
    gemm_k<false><<<dim3(8, 16, 1), blk, 0, stream>>>(
        x, Wv, bv, nullptr, v, DD, DD, DD, DD, 1, 0L,0L,0L,0L,0L,0L, 0, 1.0f);
    // 7) scores[b,h,i,j] = (q.k^T)/8   batched over z=(b,h)
    gemm_k<true><<<dim3(8, 8, 16), blk, 0, stream>>>(
        q, kb, nullptr, nullptr, sc, DH, DD, DD, SS,
        HH, 262144L, 64L, 262144L, 64L, 2097152L, 262144L, 0, 0.125f);
    // 8) attn = softmax(scores)  in-place
    softmax_k<<<dim3(BB * HH * SS), blk, 0, stream>>>(sc);
    // 9) attn_avg = mean_h attn
    aavg_k<<<dim3(2048), blk, 0, stream>>>(sc, av);
    // 10) ctx[b,i,h*64+dh] = attn @ v   batched over z=(b,h)
    gemm_k<false><<<dim3(1, 8, 16), blk, 0, stream>>>(
        sc, v, nullptr, nullptr, ctx, SS, SS, DD, DD,
        HH, 2097152L, 262144L, 262144L, 64L, 262144L, 64L, 0, 1.0f);
    // 11) x_out = x + ctx @ Wo + bo  -> d_out
    gemm_k<false><<<dim3(8, 16, 1), blk, 0, stream>>>(
        ctx, Wo, bo, x, xout, DD, DD, DD, DD, 1, 0L,0L,0L,0L,0L,0L, 0, 1.0f);
    // 12) u_proj = u @ Wfp + bfp   [1024,512]
    gemm_k<false><<<dim3(8, 16, 1), blk, 0, stream>>>(
        u, Wfp, bfp, nullptr, up, DF, DF, DD, DD, 1, 0L,0L,0L,0L,0L,0L, 0, 1.0f);
    // 13) u_t = sum_j aavg * Gamma @ u_chunks
    ut_k<<<dim3(1024), dim3(512), 0, stream>>>(Gm, av, up, ut);
    // 14) u_out = u + u_t @ Wfo + bfo  -> d_out (offset 524288)
    gemm_k<false><<<dim3(1, 16, 1), blk, 0, stream>>>(
        ut, Wfo, bfo, u, uout, DD, DD, DF, DF, 1, 0L,0L,0L,0L,0L,0L, 0, 1.0f);
}

// Round 2
// 1323.929 us; speedup vs baseline: 3.2766x; 3.2766x over previous
//
#include <hip/hip_runtime.h>
#include <math.h>

// B,S,D,K,DF,H,DFF = 2,512,512,8,64,8,2048
#define BB 2
#define SS 512
#define DD 512
#define HH 8
#define DFF 2048

typedef __attribute__((ext_vector_type(8))) short bf16x8;
typedef __attribute__((ext_vector_type(4))) float f32x4;

__device__ __forceinline__ float gelu_exact(float v) {
    return 0.5f * v * (1.0f + erff(v * 0.70710678118654752f));
}
__device__ __forceinline__ unsigned short f2bf(float f) {
    unsigned u = __float_as_uint(f);
    u += 0x7FFF + ((u >> 16) & 1);
    return (unsigned short)(u >> 16);
}
__device__ __forceinline__ float bf2f(unsigned short s) {
    return __uint_as_float(((unsigned)s) << 16);
}
__device__ __forceinline__ void gload16(const void* g, void* l) {
    __builtin_amdgcn_global_load_lds((const __attribute__((address_space(1))) void*)g,
                                     (__attribute__((address_space(3))) void*)l, 16, 0, 0);
}

// ---------------- bf16 MFMA GEMM: C = epi(A @ B^T + bias) ----------------
// A [M,K] bf16 row-major, B [N,K] bf16 row-major (i.e. B^T layout).
// 128x128 tile, BK=32, 256 threads (4 waves, 2x2), 16x16x32 MFMA.
// EPI 1: bias[col] + gelu -> fp32 out.  EPI 2: bias[(col&511)*64+(col>>9)] -> bf16 out.
template<int EPI>
__global__ __launch_bounds__(256)
void mgemm_k(const unsigned short* __restrict__ A, const unsigned short* __restrict__ B,
             const float* __restrict__ bias, float* __restrict__ Cf,
             unsigned short* __restrict__ Cb, int M, int N, int K)
{
    __shared__ unsigned short As[128][32];
    __shared__ unsigned short Bs[128][32];
    const int tid = threadIdx.x;
    const int wave = tid >> 6, lane = tid & 63;
    const int row0 = blockIdx.y * 128, col0 = blockIdx.x * 128;
    const int wm = wave >> 1, wn = wave & 1;
    const int lm = lane & 15, quad = lane >> 4;
    const int lrow = lane >> 2;        // 0..15
    const int lk   = (lane & 3) * 8;   // 0,8,16,24
    f32x4 acc[4][4];
    #pragma unroll
    for (int i = 0; i < 4; ++i)
        #pragma unroll
        for (int j = 0; j < 4; ++j) acc[i][j] = (f32x4)0.f;

    const unsigned short* Ab = A + (long)row0 * K;
    const unsigned short* Bb = B + (long)col0 * K;

    for (int k0 = 0; k0 < K; k0 += 32) {
        #pragma unroll
        for (int t = 0; t < 2; ++t) {
            const int r = wave * 32 + t * 16;
            gload16(Ab + (long)(r + lrow) * K + k0 + lk, &As[r][0]);
            gload16(Bb + (long)(r + lrow) * K + k0 + lk, &Bs[r][0]);
        }
        __syncthreads();
        bf16x8 af[4], bfr[4];
        #pragma unroll
        for (int mt = 0; mt < 4; ++mt)
            af[mt] = *(const bf16x8*)&As[wm * 64 + mt * 16 + lm][quad * 8];
        #pragma unroll
        for (int nt = 0; nt < 4; ++nt)
            bfr[nt] = *(const bf16x8*)&Bs[wn * 64 + nt * 16 + lm][quad * 8];
        #pragma unroll
        for (int mt = 0; mt < 4; ++mt)
            #pragma unroll
            for (int nt = 0; nt < 4; ++nt)
                acc[mt][nt] = __builtin_amdgcn_mfma_f32_16x16x32_bf16(
                    af[mt], bfr[nt], acc[mt][nt], 0, 0, 0);
        __syncthreads();
    }
    #pragma unroll
    for (int mt = 0; mt < 4; ++mt) {
        #pragma unroll
        for (int nt = 0; nt < 4; ++nt) {
            #pragma unroll
            for (int r = 0; r < 4; ++r) {
                const int row = row0 + wm * 64 + mt * 16 + quad * 4 + r;
                const int col = col0 + wn * 64 + nt * 16 + lm;
                float v = acc[mt][nt][r];
                if (EPI == 2) v += bias[(col & 511) * 64 + (col >> 9)];
                else          v += bias[col];
                if (EPI == 1) v = gelu_exact(v);
                if (EPI == 2) Cb[(long)row * N + col] = f2bf(v);
                else          Cf[(long)row * N + col] = v;
            }
        }
    }
}

// ------------- fused lie-GEMM + 6-term Taylor matexp -> Gamma -------------
// Per block: b, j, 128 i's. lie[i,kl] = x_i . At[b,j,kl,:], M = xa - lie,
// Gamma = exp(M). Grid (4, 512, 2), 256 threads.
__global__ __launch_bounds__(256)
void liegamma_k(const unsigned short* __restrict__ xb, const unsigned short* __restrict__ At,
                const float* __restrict__ xa, float* __restrict__ Gamma)
{
    __shared__ unsigned short Xs[128][32];
    __shared__ unsigned short Ts[64][32];
    __shared__ float Ml[128][68];   // stride 68: 8 groups hit distinct bank quads
    const int tid = threadIdx.x;
    const int wave = tid >> 6, lane = tid & 63;
    const int b = blockIdx.z, j = blockIdx.y;
    const int i0 = blockIdx.x * 128;
    const int lm = lane & 15, quad = lane >> 4;
    const int lrow = lane >> 2, lk = (lane & 3) * 8;
    const unsigned short* Xb = xb + ((long)b * 512 + i0) * 512;
    const unsigned short* Tb = At + ((long)(b * 512 + j)) * 32768;
    f32x4 acc[2][4];
    #pragma unroll
    for (int i = 0; i < 2; ++i)
        #pragma unroll
        for (int n = 0; n < 4; ++n) acc[i][n] = (f32x4)0.f;

    for (int k0 = 0; k0 < 512; k0 += 32) {
        #pragma unroll
        for (int t = 0; t < 2; ++t) {
            const int r = wave * 32 + t * 16;
            gload16(Xb + (long)(r + lrow) * 512 + k0 + lk, &Xs[r][0]);
        }
        {
            const int r = wave * 16;
            gload16(Tb + (long)(r + lrow) * 512 + k0 + lk, &Ts[r][0]);
        }
        __syncthreads();
        bf16x8 af[2], bfr[4];
        #pragma unroll
        for (int mt = 0; mt < 2; ++mt)
            af[mt] = *(const bf16x8*)&Xs[wave * 32 + mt * 16 + lm][quad * 8];
        #pragma unroll
        for (int nt = 0; nt < 4; ++nt)
            bfr[nt] = *(const bf16x8*)&Ts[nt * 16 + lm][quad * 8];
        #pragma unroll
        for (int mt = 0; mt < 2; ++mt)
            #pragma unroll
            for (int nt = 0; nt < 4; ++nt)
                acc[mt][nt] = __builtin_amdgcn_mfma_f32_16x16x32_bf16(
                    af[mt], bfr[nt], acc[mt][nt], 0, 0, 0);
        __syncthreads();
    }
    // M = xa_j - lie  into LDS
    const float* xar = xa + ((long)(b * 512 + j)) * 64;
    #pragma unroll
    for (int mt = 0; mt < 2; ++mt)
        #pragma unroll
        for (int nt = 0; nt < 4; ++nt) {
            const float xv = xar[nt * 16 + lm];
            #pragma unroll
            for (int r = 0; r < 4; ++r)
                Ml[wave * 32 + mt * 16 + quad * 4 + r][nt * 16 + lm] = xv - acc[mt][nt][r];
        }
    __syncthreads();
    // matexp: 8 lanes per 8x8 matrix; lane owns row r8. 4 passes of 32 matrices.
    const int r8 = tid & 7, mg = tid >> 3;
    #pragma unroll
    for (int pass = 0; pass < 4; ++pass) {
        const int mi = pass * 32 + mg;
        const f32x4* Mr = (const f32x4*)&Ml[mi][0];
        float P[8], res[8];
        #pragma unroll
        for (int c = 0; c < 8; ++c) { const float iv = (c == r8) ? 1.f : 0.f; P[c] = iv; res[c] = iv; }
        #pragma unroll
        for (int n = 1; n <= 6; ++n) {
            float tmp[8] = {0.f,0.f,0.f,0.f,0.f,0.f,0.f,0.f};
            const float invn = 1.f / (float)n;
            #pragma unroll
            for (int l = 0; l < 8; ++l) {
                const f32x4 m0 = Mr[l * 2], m1 = Mr[l * 2 + 1];
                const float pl = P[l];
                #pragma unroll
                for (int c = 0; c < 4; ++c) {
                    tmp[c]     = fmaf(pl, m0[c], tmp[c]);
                    tmp[4 + c] = fmaf(pl, m1[c], tmp[4 + c]);
                }
            }
            #pragma unroll
            for (int c = 0; c < 8; ++c) { P[c] = tmp[c] * invn; res[c] += P[c]; }
        }
        f32x4* outp = (f32x4*)(Gamma + ((((long)(b * 512 + i0 + mi)) * 512 + j) * 64 + r8 * 8));
        outp[0] = *(const f32x4*)&res[0];
        outp[1] = *(const f32x4*)&res[4];
    }
}

// ---------------- fp32 tiled GEMM (small ops: attention etc.) ----------------
#define TILE 64
#define BK 16
template<bool TRANSB>
__global__ __launch_bounds__(256)
void gemm_k(const float* __restrict__ Ab, const float* __restrict__ Bb,
            const float* __restrict__ bias, const float* __restrict__ resid,
            float* __restrict__ Cb,
            int K, int lda, int ldb, int ldc,
            int batchH,
            long aSB, long aSH, long bSB, long bSH, long cSB, long cSH,
            int act, float scale)
{
    __shared__ float As[BK][TILE + 1];
    __shared__ float Bs[BK][TILE + 1];
    const int z = blockIdx.z;
    const int zb = z / batchH, zh = z % batchH;
    const float* A = Ab + (long)zb * aSB + (long)zh * aSH;
    const float* B = Bb + (long)zb * bSB + (long)zh * bSH;
    float* C = Cb + (long)zb * cSB + (long)zh * cSH;
    const int tid = threadIdx.x;
    const int tx = tid & 15, ty = tid >> 4;
    const int row0 = blockIdx.y * TILE;
    const int col0 = blockIdx.x * TILE;
    float acc[4][4] = {};
    for (int k0 = 0; k0 < K; k0 += BK) {
        {
            const int kk = tid & 15;
            const int m0 = tid >> 4;
            #pragma unroll
            for (int p = 0; p < 4; ++p) {
                const int m = m0 + p * 16;
                As[kk][m] = A[(long)(row0 + m) * lda + (k0 + kk)];
            }
        }
        if (!TRANSB) {
            const int n = tid & 63;
            const int kq = tid >> 6;
            #pragma unroll
            for (int p = 0; p < 4; ++p) {
                const int kk = kq + p * 4;
                Bs[kk][n] = B[(long)(k0 + kk) * ldb + (col0 + n)];
            }
        } else {
            const int kk = tid & 15;
            const int n0 = tid >> 4;
            #pragma unroll
            for (int p = 0; p < 4; ++p) {
                const int n = n0 + p * 16;
                Bs[kk][n] = B[(long)(col0 + n) * ldb + (k0 + kk)];
            }
        }
        __syncthreads();
        #pragma unroll
        for (int kk = 0; kk < BK; ++kk) {
            float a[4], b[4];
            #pragma unroll
            for (int i = 0; i < 4; ++i) a[i] = As[kk][ty * 4 + i];
            #pragma unroll
            for (int j = 0; j < 4; ++j) b[j] = Bs[kk][tx * 4 + j];
            #pragma unroll
            for (int i = 0; i < 4; ++i)
                #pragma unroll
                for (int j = 0; j < 4; ++j)
                    acc[i][j] = fmaf(a[i], b[j], acc[i][j]);
        }
        __syncthreads();
    }
    #pragma unroll
    for (int i = 0; i < 4; ++i) {
        const int r = row0 + ty * 4 + i;
        #pragma unroll
        for (int j = 0; j < 4; ++j) {
            const int c = col0 + tx * 4 + j;
            float v = acc[i][j] * scale;
            if (bias)  v += bias[c];
            if (act == 1) v = gelu_exact(v);
            if (resid) v += resid[(long)r * ldc + c];
            C[(long)r * ldc + c] = v;
        }
    }
}

// LayerNorm over last dim (2048) -> bf16 out. One block per row.
__global__ __launch_bounds__(256)
void lnbf_k(const float* __restrict__ h, const float* __restrict__ g,
            const float* __restrict__ b, unsigned short* __restrict__ out)
{
    const long row = blockIdx.x;
    const float* r = h + row * (long)DFF;
    const int tid = threadIdx.x;
    float vals[8];
    float s = 0.f, sq = 0.f;
    #pragma unroll
    for (int e = 0; e < 8; ++e) {
        const float v = r[tid + e * 256];
        vals[e] = v; s += v; sq += v * v;
    }
    __shared__ float rs[256], rq[256];
    rs[tid] = s; rq[tid] = sq; __syncthreads();
    for (int st = 128; st > 0; st >>= 1) {
        if (tid < st) { rs[tid] += rs[tid + st]; rq[tid] += rq[tid + st]; }
        __syncthreads();
    }
    const float mean = rs[0] * (1.f / DFF);
    const float var  = rq[0] * (1.f / DFF) - mean * mean;
    const float inv  = rsqrtf(var + 1e-5f);
    unsigned short* o = out + row * (long)DFF;
    #pragma unroll
    for (int e = 0; e < 8; ++e) {
        const int c = tid + e * 256;
        o[c] = f2bf((vals[e] - mean) * inv * g[c] + b[c]);
    }
}

// xa[bj,kl] = sum_d x[bj,d] * At[bj,kl,d]. 1024 blocks, 256 thr.
__global__ __launch_bounds__(256)
void xa_k(const float* __restrict__ x, const unsigned short* __restrict__ At,
          float* __restrict__ xa)
{
    const int bj = blockIdx.x;
    const int tid = threadIdx.x;
    const int kl = tid >> 2, q = tid & 3;
    const unsigned short* Ar = At + (long)bj * 32768 + kl * 512 + q * 128;
    const float* xr = x + (long)bj * 512 + q * 128;
    float s = 0.f;
    for (int d = 0; d < 128; ++d) s = fmaf(xr[d], bf2f(Ar[d]), s);
    __shared__ float red[64][5];
    red[kl][q] = s; __syncthreads();
    if (q == 0)
        xa[(long)bj * 64 + kl] = red[kl][0] + red[kl][1] + red[kl][2] + red[kl][3];
}

// Softmax over last dim (512), in-place.
__global__ __launch_bounds__(256)
void softmax_k(float* __restrict__ p)
{
    const long row = blockIdx.x;
    float* r = p + row * 512;
    const int tid = threadIdx.x;
    float v0 = r[tid], v1 = r[tid + 256];
    __shared__ float red[256];
    red[tid] = fmaxf(v0, v1); __syncthreads();
    for (int s = 128; s > 0; s >>= 1) {
        if (tid < s) red[tid] = fmaxf(red[tid], red[tid + s]);
        __syncthreads();
    }
    const float m = red[0]; __syncthreads();
    v0 = expf(v0 - m); v1 = expf(v1 - m);
    red[tid] = v0 + v1; __syncthreads();
    for (int s = 128; s > 0; s >>= 1) {
        if (tid < s) red[tid] += red[tid + s];
        __syncthreads();
    }
    const float inv = 1.f / red[0];
    r[tid] = v0 * inv; r[tid + 256] = v1 * inv;
}

__global__ __launch_bounds__(256)
void aavg_k(const float* __restrict__ attn, float* __restrict__ aavg)
{
    const long idx = (long)blockIdx.x * 256 + threadIdx.x;
    const int b = (int)(idx >> 18);
    const long rem = idx & 262143;
    float s = 0.f;
    #pragma unroll
    for (int h = 0; h < HH; ++h)
        s += attn[(long)b * 2097152 + (long)h * 262144 + rem];
    aavg[idx] = s * 0.125f;
}

// u_t[b,i,k,c] = sum_j aavg * sum_l Gamma[b,i,j,k,l] * uproj[b,j,l*64+c]
__global__ __launch_bounds__(512)
void ut_k(const float* __restrict__ Gamma, const float* __restrict__ aavg,
          const float* __restrict__ uproj, float* __restrict__ ut)
{
    const int bi = blockIdx.x;
    const int b = bi >> 9;
    const int tid = threadIdx.x;
    const int k = tid >> 6, c = tid & 63;
    __shared__ float Gs[8][64];
    __shared__ float Us[8][512];
    __shared__ float as_[8];
    const float* Grow = Gamma + (long)bi * 512 * 64;
    const float* arow = aavg + (long)bi * 512;
    const float* ub   = uproj + (long)b * 512 * 512;
    float acc = 0.f;
    for (int j0 = 0; j0 < 512; j0 += 8) {
        {
            const int jj = tid >> 6, kl = tid & 63;
            Gs[jj][kl] = Grow[(long)(j0 + jj) * 64 + kl];
        }
        #pragma unroll
        for (int rr = 0; rr < 8; ++rr)
            Us[rr][tid] = ub[(long)(j0 + rr) * 512 + tid];
        if (tid < 8) as_[tid] = arow[j0 + tid];
        __syncthreads();
        #pragma unroll
        for (int jj = 0; jj < 8; ++jj) {
            float s = 0.f;
            #pragma unroll
            for (int l = 0; l < 8; ++l)
                s = fmaf(Gs[jj][k * 8 + l], Us[jj][l * 64 + c], s);
            acc = fmaf(as_[jj], s, acc);
        }
        __syncthreads();
    }
    ut[(long)bi * 512 + tid] = acc;
}

// Wc1 [R=512][C=2048] fp32 -> out [C][R] bf16 (plain transpose)
__global__ __launch_bounds__(256)
void tconv_k(const float* __restrict__ in, unsigned short* __restrict__ out,
             int R, int C)
{
    __shared__ float Ls[64][65];
    const int c0 = blockIdx.x * 64, r0 = blockIdx.y * 64;
    const int tid = threadIdx.x;
    const int tc = tid & 63, tr = tid >> 6;
    #pragma unroll
    for (int p = 0; p < 16; ++p)
        Ls[tr + p * 4][tc] = in[(long)(r0 + tr + p * 4) * C + c0 + tc];
    __syncthreads();
    #pragma unroll
    for (int p = 0; p < 16; ++p)
        out[(long)(c0 + tr + p * 4) * R + r0 + tc] = f2bf(Ls[tc][tr + p * 4]);
}

// Wc2 [2048][32768] fp32 -> Wc2p [32768][2048] bf16 with row perm:
// out[kl*512 + d][f] = in[f][d*64 + kl]
__global__ __launch_bounds__(256)
void wc2p_k(const float* __restrict__ in, unsigned short* __restrict__ out)
{
    __shared__ float Ls[64][65];
    const int d0 = blockIdx.x;            // cols d0*64 .. +63 (kl = 0..63)
    const long f0 = blockIdx.y * 64;
    const int tid = threadIdx.x;
    const int tc = tid & 63, tr = tid >> 6;
    #pragma unroll
    for (int p = 0; p < 16; ++p)
        Ls[tr + p * 4][tc] = in[(f0 + tr + p * 4) * 32768 + (long)d0 * 64 + tc];
    __syncthreads();
    #pragma unroll
    for (int p = 0; p < 16; ++p) {
        const int kl = tr + p * 4;
        out[((long)kl * 512 + d0) * 2048 + f0 + tc] = f2bf(Ls[tc][kl]);
    }
}

__global__ __launch_bounds__(256)
void f2bf_k(const float* __restrict__ in, unsigned short* __restrict__ out, int n)
{
    const int i = blockIdx.x * 256 + threadIdx.x;
    if (i < n) out[i] = f2bf(in[i]);
}

extern "C" void kernel_launch(void* const* d_in, const int* in_sizes, int n_in,
                              void* d_out, int out_size, void* d_ws, size_t ws_size,
                              hipStream_t stream) {
    const float* x   = (const float*)d_in[0];
    const float* u   = (const float*)d_in[1];
    const float* Wq  = (const float*)d_in[2];  const float* bq  = (const float*)d_in[3];
    const float* Wk  = (const float*)d_in[4];  const float* bk  = (const float*)d_in[5];
    const float* Wv  = (const float*)d_in[6];  const float* bv  = (const float*)d_in[7];
    const float* Wo  = (const float*)d_in[8];  const float* bo  = (const float*)d_in[9];
    const float* Wfp = (const float*)d_in[10]; const float* bfp = (const float*)d_in[11];
    const float* Wfo = (const float*)d_in[12]; const float* bfo = (const float*)d_in[13];
    const float* Wc1 = (const float*)d_in[14]; const float* bc1 = (const float*)d_in[15];
    const float* gln = (const float*)d_in[16]; const float* bln = (const float*)d_in[17];
    const float* Wc2 = (const float*)d_in[18]; const float* bc2 = (const float*)d_in[19];

    float* ws = (float*)d_ws;
    // Layout (float offsets). Gamma aliases Wc2p (dead after fc2);
    // attention aliases At (dead after liegamma). Peak ~217 MB.
    float*          h    = ws;                                        // 2,097,152 f
    unsigned short* Wc2p = (unsigned short*)(ws + 2097152);           // 33,554,432 f
    float*          Gm   = ws + 2097152;                              // alias of Wc2p
    unsigned short* At   = (unsigned short*)(ws + 35651584);          // 16,777,216 f
    float*          att  = ws + 35651584;                             // alias of At
    unsigned short* h_bf = (unsigned short*)(ws + 52428800);          // 1,048,576 f
    unsigned short* x_bf = (unsigned short*)(ws + 53477376);          //   262,144 f
    unsigned short* Wc1t = (unsigned short*)(ws + 53739520);          //   524,288 f
    float*          xa   = ws + 54263808;                             //    65,536 f

    float* q   = att;
    float* kb  = att + 524288;
    float* v   = att + 1048576;
    float* sc  = att + 1572864;    // 4,194,304
    float* av  = att + 5767168;
    float* ctx = att + 6291456;
    float* up  = att + 6815744;
    float* ut  = att + 7340032;
    float* xout = (float*)d_out;
    float* uout = xout + 524288;

    const dim3 blk(256);

    // conversions
    tconv_k<<<dim3(32, 8), blk, 0, stream>>>(Wc1, Wc1t, 512, 2048);
    wc2p_k<<<dim3(512, 32), blk, 0, stream>>>(Wc2, Wc2p);
    f2bf_k<<<dim3(2048), blk, 0, stream>>>(x, x_bf, 524288);

    // fc1: h = gelu(x @ Wc1 + bc1)  [1024,2048]  (MFMA)
    mgemm_k<1><<<dim3(16, 8), blk, 0, stream>>>(
        x_bf, Wc1t, bc1, h, nullptr, 1024, 2048, 512);
    // LN -> bf16
    lnbf_k<<<dim3(1024), blk, 0, stream>>>(h, gln, bln, h_bf);
    // fc2 (permuted): At[bj, kl*512+d] = h @ Wc2 + bc2  (MFMA, bf16 out)
    mgemm_k<2><<<dim3(256, 8), blk, 0, stream>>>(
        h_bf, Wc2p, bc2, nullptr, At, 1024, 32768, 2048);
    // xa
    xa_k<<<dim3(1024), blk, 0, stream>>>(x, At, xa);
    // Gamma (fused lie GEMM + matexp)
    liegamma_k<<<dim3(4, 512, 2), blk, 0, stream>>>(x_bf, At, xa, Gm);

    // attention (fp32), buffers alias dead At region
    gemm_k<false><<<dim3(8, 16, 1), blk, 0, stream>>>(
        x, Wq, bq, nullptr, q, DD, DD, DD, DD, 1, 0L,0L,0L,0L,0L,0L, 0, 1.0f);
    gemm_k<false><<<dim3(8, 16, 1), blk, 0, stream>>>(
        x, Wk, bk, nullptr, kb, DD, DD, DD, DD, 1, 0L,0L,0L,0L,0L,0L, 0, 1.0f);
    gemm_k<false><<<dim3(8, 16, 1), blk, 0, stream>>>(
        x, Wv, bv, nullptr, v, DD, DD, DD, DD, 1, 0L,0L,0L,0L,0L,0L, 0, 1.0f);
    gemm_k<true><<<dim3(8, 8, 16), blk, 0, stream>>>(
        q, kb, nullptr, nullptr, sc, 64, DD, DD, SS,
        HH, 262144L, 64L, 262144L, 64L, 2097152L, 262144L, 0, 0.125f);
    softmax_k<<<dim3(BB * HH * SS), blk, 0, stream>>>(sc);
    aavg_k<<<dim3(2048), blk, 0, stream>>>(sc, av);
    gemm_k<false><<<dim3(1, 8, 16), blk, 0, stream>>>(
        sc, v, nullptr, nullptr, ctx, SS, SS, DD, DD,
        HH, 2097152L, 262144L, 262144L, 64L, 262144L, 64L, 0, 1.0f);
    gemm_k<false><<<dim3(8, 16, 1), blk, 0, stream>>>(
        ctx, Wo, bo, x, xout, DD, DD, DD, DD, 1, 0L,0L,0L,0L,0L,0L, 0, 1.0f);

    // fiber transport
    gemm_k<false><<<dim3(8, 16, 1), blk, 0, stream>>>(
        u, Wfp, bfp, nullptr, up, 64, 64, DD, DD, 1, 0L,0L,0L,0L,0L,0L, 0, 1.0f);
    ut_k<<<dim3(1024), dim3(512), 0, stream>>>(Gm, av, up, ut);
    gemm_k<false><<<dim3(1, 16, 1), blk, 0, stream>>>(
        ut, Wfo, bfo, u, uout, DD, DD, 64, 64, 1, 0L,0L,0L,0L,0L,0L, 0, 1.0f);
}

// Round 3
// 1020.504 us; speedup vs baseline: 4.2508x; 1.2973x over previous
//
#include <hip/hip_runtime.h>
#include <math.h>

// B,S,D,K,DF,H,DFF = 2,512,512,8,64,8,2048
#define BB 2
#define SS 512
#define DD 512
#define HH 8
#define DFF 2048

typedef __attribute__((ext_vector_type(8))) short bf16x8;
typedef __attribute__((ext_vector_type(4))) float f32x4;

__device__ __forceinline__ float gelu_exact(float v) {
    return 0.5f * v * (1.0f + erff(v * 0.70710678118654752f));
}
__device__ __forceinline__ unsigned short f2bf(float f) {
    unsigned u = __float_as_uint(f);
    u += 0x7FFF + ((u >> 16) & 1);
    return (unsigned short)(u >> 16);
}
__device__ __forceinline__ float bf2f(unsigned short s) {
    return __uint_as_float(((unsigned)s) << 16);
}
__device__ __forceinline__ void gload16(const void* g, void* l) {
    __builtin_amdgcn_global_load_lds((const __attribute__((address_space(1))) void*)g,
                                     (__attribute__((address_space(3))) void*)l, 16, 0, 0);
}

// ---------------- flexible bf16 MFMA GEMM: C = epi(A @ B^T) ----------------
// A [M,K] bf16 (lda), B [N,K] bf16 (ldb, i.e. B^T layout). 128xNT tile, BK=32,
// 256 threads (4 waves 2x2), 16x16x32 MFMA. Batched over blockIdx.z.
// EPI: 0 fp32 out (scale, no bias) | 1 fp32 bias+gelu | 2 bf16 perm-bias (fc2)
//      3 bf16 out (+opt bias)      | 4 fp32 bias+resid | 5 bf16 vT-store
//      6 bf16 upT2-store
template<int NT, int EPI>
__global__ __launch_bounds__(256)
void mgemm_k(const unsigned short* __restrict__ A, const unsigned short* __restrict__ B,
             const float* __restrict__ bias, const float* __restrict__ resid,
             float* __restrict__ Cf, unsigned short* __restrict__ Cb,
             int K, int lda, int ldb, int ldc, int batchH,
             long aSB, long aSH, long bSB, long bSH, long cSB, long cSH,
             float scale)
{
    __shared__ unsigned short As[128][32];
    __shared__ unsigned short Bs[NT][32];
    const int tid = threadIdx.x;
    const int wave = tid >> 6, lane = tid & 63;
    const int z = blockIdx.z;
    const int zb = z / batchH, zh = z % batchH;
    const unsigned short* Ab = A + (long)zb * aSB + (long)zh * aSH;
    const unsigned short* Bb = B + (long)zb * bSB + (long)zh * bSH;
    const int row0 = blockIdx.y * 128, col0 = blockIdx.x * NT;
    const int wm = wave >> 1, wn = wave & 1;
    const int lm = lane & 15, quad = lane >> 4;
    const int lrow = lane >> 2, lk = (lane & 3) * 8;
    constexpr int NTW = NT / 32;     // n-subtiles per wave
    f32x4 acc[4][NTW];
    #pragma unroll
    for (int i = 0; i < 4; ++i)
        #pragma unroll
        for (int j = 0; j < NTW; ++j) acc[i][j] = (f32x4)0.f;

    for (int k0 = 0; k0 < K; k0 += 32) {
        #pragma unroll
        for (int t = 0; t < 2; ++t) {
            const int r = wave * 32 + t * 16;
            gload16(Ab + (long)(row0 + r + lrow) * lda + k0 + lk, &As[r][0]);
        }
        if (NT == 128) {
            #pragma unroll
            for (int t = 0; t < 2; ++t) {
                const int r = wave * 32 + t * 16;
                gload16(Bb + (long)(col0 + r + lrow) * ldb + k0 + lk, &Bs[r][0]);
            }
        } else {
            const int r = wave * 16;
            gload16(Bb + (long)(col0 + r + lrow) * ldb + k0 + lk, &Bs[r][0]);
        }
        __syncthreads();
        bf16x8 af[4], bfr[NTW];
        #pragma unroll
        for (int mt = 0; mt < 4; ++mt)
            af[mt] = *(const bf16x8*)&As[wm * 64 + mt * 16 + lm][quad * 8];
        #pragma unroll
        for (int nt = 0; nt < NTW; ++nt)
            bfr[nt] = *(const bf16x8*)&Bs[wn * (NT / 2) + nt * 16 + lm][quad * 8];
        #pragma unroll
        for (int mt = 0; mt < 4; ++mt)
            #pragma unroll
            for (int nt = 0; nt < NTW; ++nt)
                acc[mt][nt] = __builtin_amdgcn_mfma_f32_16x16x32_bf16(
                    af[mt], bfr[nt], acc[mt][nt], 0, 0, 0);
        __syncthreads();
    }
    float* Cfz = Cf ? Cf + (long)zb * cSB + (long)zh * cSH : nullptr;
    unsigned short* Cbz = Cb ? Cb + (long)zb * cSB + (long)zh * cSH : nullptr;
    #pragma unroll
    for (int mt = 0; mt < 4; ++mt) {
        #pragma unroll
        for (int nt = 0; nt < NTW; ++nt) {
            #pragma unroll
            for (int r = 0; r < 4; ++r) {
                const int row = row0 + wm * 64 + mt * 16 + quad * 4 + r;
                const int col = col0 + wn * (NT / 2) + nt * 16 + lm;
                float v = acc[mt][nt][r] * scale;
                if (EPI == 2)      v += bias[(col & 511) * 64 + (col >> 9)];
                else if (EPI == 1 || EPI == 4) v += bias[col];
                else if ((EPI == 3 || EPI == 5 || EPI == 6) && bias) v += bias[col];
                if (EPI == 1) v = gelu_exact(v);
                if (EPI == 4) v += resid[(long)row * ldc + col];
                if (EPI == 0 || EPI == 1 || EPI == 4)
                    Cfz[(long)row * ldc + col] = v;
                else if (EPI == 2 || EPI == 3)
                    Cbz[(long)row * ldc + col] = f2bf(v);
                else if (EPI == 5)  // vT[b][h][c][j]: rows=(b,j), col=h*64+c
                    Cb[(long)(row >> 9) * 262144 + (col >> 6) * 32768 +
                       (col & 63) * 512 + (row & 511)] = f2bf(v);
                else if (EPI == 6)  // upT2[b][c][j*8+l]: rows=(b,j), col=l*64+c
                    Cb[(long)(row >> 9) * 262144 + (col & 63) * 4096 +
                       (row & 511) * 8 + (col >> 6)] = f2bf(v);
            }
        }
    }
}

// ------------- fused lie-GEMM + 6-term Taylor matexp -> Gw (bf16) -------------
// Per block: b, j, 128 i's. lie[i,kl] = x_i . At[b,j,kl,:], M = xa - lie,
// Gamma = exp(M); Gw[b][k][i][j*8+l] = f2bf(aavg[b,i,j] * Gamma[k][l]).
// Grid (4, 512, 2), 256 threads.
__global__ __launch_bounds__(256)
void liegamma_k(const unsigned short* __restrict__ xb, const unsigned short* __restrict__ At,
                const float* __restrict__ xa, const float* __restrict__ aavg,
                unsigned short* __restrict__ Gw)
{
    __shared__ unsigned short Xs[128][32];
    __shared__ unsigned short Ts[64][32];
    __shared__ float Ml[128][68];
    const int tid = threadIdx.x;
    const int wave = tid >> 6, lane = tid & 63;
    const int b = blockIdx.z, j = blockIdx.y;
    const int i0 = blockIdx.x * 128;
    const int lm = lane & 15, quad = lane >> 4;
    const int lrow = lane >> 2, lk = (lane & 3) * 8;
    const unsigned short* Xb = xb + ((long)b * 512 + i0) * 512;
    const unsigned short* Tb = At + ((long)(b * 512 + j)) * 32768;
    f32x4 acc[2][4];
    #pragma unroll
    for (int i = 0; i < 2; ++i)
        #pragma unroll
        for (int n = 0; n < 4; ++n) acc[i][n] = (f32x4)0.f;

    for (int k0 = 0; k0 < 512; k0 += 32) {
        #pragma unroll
        for (int t = 0; t < 2; ++t) {
            const int r = wave * 32 + t * 16;
            gload16(Xb + (long)(r + lrow) * 512 + k0 + lk, &Xs[r][0]);
        }
        {
            const int r = wave * 16;
            gload16(Tb + (long)(r + lrow) * 512 + k0 + lk, &Ts[r][0]);
        }
        __syncthreads();
        bf16x8 af[2], bfr[4];
        #pragma unroll
        for (int mt = 0; mt < 2; ++mt)
            af[mt] = *(const bf16x8*)&Xs[wave * 32 + mt * 16 + lm][quad * 8];
        #pragma unroll
        for (int nt = 0; nt < 4; ++nt)
            bfr[nt] = *(const bf16x8*)&Ts[nt * 16 + lm][quad * 8];
        #pragma unroll
        for (int mt = 0; mt < 2; ++mt)
            #pragma unroll
            for (int nt = 0; nt < 4; ++nt)
                acc[mt][nt] = __builtin_amdgcn_mfma_f32_16x16x32_bf16(
                    af[mt], bfr[nt], acc[mt][nt], 0, 0, 0);
        __syncthreads();
    }
    const float* xar = xa + ((long)(b * 512 + j)) * 64;
    #pragma unroll
    for (int mt = 0; mt < 2; ++mt)
        #pragma unroll
        for (int nt = 0; nt < 4; ++nt) {
            const float xv = xar[nt * 16 + lm];
            #pragma unroll
            for (int r = 0; r < 4; ++r)
                Ml[wave * 32 + mt * 16 + quad * 4 + r][nt * 16 + lm] = xv - acc[mt][nt][r];
        }
    __syncthreads();
    const int r8 = tid & 7, mg = tid >> 3;
    #pragma unroll
    for (int pass = 0; pass < 4; ++pass) {
        const int mi = pass * 32 + mg;
        const f32x4* Mr = (const f32x4*)&Ml[mi][0];
        float P[8], res[8];
        #pragma unroll
        for (int c = 0; c < 8; ++c) { const float iv = (c == r8) ? 1.f : 0.f; P[c] = iv; res[c] = iv; }
        #pragma unroll
        for (int n = 1; n <= 6; ++n) {
            float tmp[8] = {0.f,0.f,0.f,0.f,0.f,0.f,0.f,0.f};
            const float invn = 1.f / (float)n;
            #pragma unroll
            for (int l = 0; l < 8; ++l) {
                const f32x4 m0 = Mr[l * 2], m1 = Mr[l * 2 + 1];
                const float pl = P[l];
                #pragma unroll
                for (int c = 0; c < 4; ++c) {
                    tmp[c]     = fmaf(pl, m0[c], tmp[c]);
                    tmp[4 + c] = fmaf(pl, m1[c], tmp[4 + c]);
                }
            }
            #pragma unroll
            for (int c = 0; c < 8; ++c) { P[c] = tmp[c] * invn; res[c] += P[c]; }
        }
        const float av = aavg[((long)b * 512 + i0 + mi) * 512 + j];
        bf16x8 o;
        #pragma unroll
        for (int c = 0; c < 8; ++c) o[c] = (short)f2bf(res[c] * av);
        *(bf16x8*)(Gw + ((long)(b * 8 + r8) * 512 + (i0 + mi)) * 4096 + (long)j * 8) = o;
    }
}

// LayerNorm over last dim (2048) -> bf16 out. One block per row.
__global__ __launch_bounds__(256)
void lnbf_k(const float* __restrict__ h, const float* __restrict__ g,
            const float* __restrict__ b, unsigned short* __restrict__ out)
{
    const long row = blockIdx.x;
    const float* r = h + row * (long)DFF;
    const int tid = threadIdx.x;
    float vals[8];
    float s = 0.f, sq = 0.f;
    #pragma unroll
    for (int e = 0; e < 8; ++e) {
        const float v = r[tid + e * 256];
        vals[e] = v; s += v; sq += v * v;
    }
    __shared__ float rs[256], rq[256];
    rs[tid] = s; rq[tid] = sq; __syncthreads();
    for (int st = 128; st > 0; st >>= 1) {
        if (tid < st) { rs[tid] += rs[tid + st]; rq[tid] += rq[tid + st]; }
        __syncthreads();
    }
    const float mean = rs[0] * (1.f / DFF);
    const float var  = rq[0] * (1.f / DFF) - mean * mean;
    const float inv  = rsqrtf(var + 1e-5f);
    unsigned short* o = out + row * (long)DFF;
    #pragma unroll
    for (int e = 0; e < 8; ++e) {
        const int c = tid + e * 256;
        o[c] = f2bf((vals[e] - mean) * inv * g[c] + b[c]);
    }
}

// xa[bj,kl] = sum_d x[bj,d] * At[bj,kl,d]. 1024 blocks, 256 thr.
__global__ __launch_bounds__(256)
void xa_k(const float* __restrict__ x, const unsigned short* __restrict__ At,
          float* __restrict__ xa)
{
    const int bj = blockIdx.x;
    const int tid = threadIdx.x;
    const int kl = tid >> 2, q = tid & 3;
    const unsigned short* Ar = At + (long)bj * 32768 + kl * 512 + q * 128;
    const float* xr = x + (long)bj * 512 + q * 128;
    float s = 0.f;
    for (int d = 0; d < 128; ++d) s = fmaf(xr[d], bf2f(Ar[d]), s);
    __shared__ float red[64][5];
    red[kl][q] = s; __syncthreads();
    if (q == 0)
        xa[(long)bj * 64 + kl] = red[kl][0] + red[kl][1] + red[kl][2] + red[kl][3];
}

// Softmax over last dim (512), in-place fp32 + bf16 copy.
__global__ __launch_bounds__(256)
void softmax_k(float* __restrict__ p, unsigned short* __restrict__ pb)
{
    const long row = blockIdx.x;
    float* r = p + row * 512;
    const int tid = threadIdx.x;
    float v0 = r[tid], v1 = r[tid + 256];
    __shared__ float red[256];
    red[tid] = fmaxf(v0, v1); __syncthreads();
    for (int s = 128; s > 0; s >>= 1) {
        if (tid < s) red[tid] = fmaxf(red[tid], red[tid + s]);
        __syncthreads();
    }
    const float m = red[0]; __syncthreads();
    v0 = expf(v0 - m); v1 = expf(v1 - m);
    red[tid] = v0 + v1; __syncthreads();
    for (int s = 128; s > 0; s >>= 1) {
        if (tid < s) red[tid] += red[tid + s];
        __syncthreads();
    }
    const float inv = 1.f / red[0];
    const float a0 = v0 * inv, a1 = v1 * inv;
    r[tid] = a0; r[tid + 256] = a1;
    unsigned short* rb = pb + row * 512;
    rb[tid] = f2bf(a0); rb[tid + 256] = f2bf(a1);
}

__global__ __launch_bounds__(256)
void aavg_k(const float* __restrict__ attn, float* __restrict__ aavg)
{
    const long idx = (long)blockIdx.x * 256 + threadIdx.x;
    const int b = (int)(idx >> 18);
    const long rem = idx & 262143;
    float s = 0.f;
    #pragma unroll
    for (int h = 0; h < HH; ++h)
        s += attn[(long)b * 2097152 + (long)h * 262144 + rem];
    aavg[idx] = s * 0.125f;
}

// [R][C] fp32 -> [C][R] bf16 transpose
__global__ __launch_bounds__(256)
void tconv_k(const float* __restrict__ in, unsigned short* __restrict__ out,
             int R, int C)
{
    __shared__ float Ls[64][65];
    const int c0 = blockIdx.x * 64, r0 = blockIdx.y * 64;
    const int tid = threadIdx.x;
    const int tc = tid & 63, tr = tid >> 6;
    #pragma unroll
    for (int p = 0; p < 16; ++p)
        Ls[tr + p * 4][tc] = in[(long)(r0 + tr + p * 4) * C + c0 + tc];
    __syncthreads();
    #pragma unroll
    for (int p = 0; p < 16; ++p)
        out[(long)(c0 + tr + p * 4) * R + r0 + tc] = f2bf(Ls[tc][tr + p * 4]);
}

// Wc2 [2048][32768] fp32 -> Wc2p [32768][2048] bf16: out[kl*512+d][f] = in[f][d*64+kl]
__global__ __launch_bounds__(256)
void wc2p_k(const float* __restrict__ in, unsigned short* __restrict__ out)
{
    __shared__ float Ls[64][65];
    const int d0 = blockIdx.x;
    const long f0 = blockIdx.y * 64;
    const int tid = threadIdx.x;
    const int tc = tid & 63, tr = tid >> 6;
    #pragma unroll
    for (int p = 0; p < 16; ++p)
        Ls[tr + p * 4][tc] = in[(f0 + tr + p * 4) * 32768 + (long)d0 * 64 + tc];
    __syncthreads();
    #pragma unroll
    for (int p = 0; p < 16; ++p) {
        const int kl = tr + p * 4;
        out[((long)kl * 512 + d0) * 2048 + f0 + tc] = f2bf(Ls[tc][kl]);
    }
}

__global__ __launch_bounds__(256)
void f2bf_k(const float* __restrict__ in, unsigned short* __restrict__ out, int n)
{
    const int i = blockIdx.x * 256 + threadIdx.x;
    if (i < n) out[i] = f2bf(in[i]);
}

extern "C" void kernel_launch(void* const* d_in, const int* in_sizes, int n_in,
                              void* d_out, int out_size, void* d_ws, size_t ws_size,
                              hipStream_t stream) {
    const float* x   = (const float*)d_in[0];
    const float* u   = (const float*)d_in[1];
    const float* Wq  = (const float*)d_in[2];  const float* bq  = (const float*)d_in[3];
    const float* Wk  = (const float*)d_in[4];  const float* bk  = (const float*)d_in[5];
    const float* Wv  = (const float*)d_in[6];  const float* bv  = (const float*)d_in[7];
    const float* Wo  = (const float*)d_in[8];  const float* bo  = (const float*)d_in[9];
    const float* Wfp = (const float*)d_in[10]; const float* bfp = (const float*)d_in[11];
    const float* Wfo = (const float*)d_in[12]; const float* bfo = (const float*)d_in[13];
    const float* Wc1 = (const float*)d_in[14]; const float* bc1 = (const float*)d_in[15];
    const float* gln = (const float*)d_in[16]; const float* bln = (const float*)d_in[17];
    const float* Wc2 = (const float*)d_in[18]; const float* bc2 = (const float*)d_in[19];

    float* ws = (float*)d_ws;
    // float-unit offsets; Gw aliases Wc2p (dead after fc2). Peak ~253 MB.
    unsigned short* Wc2p = (unsigned short*)(ws);                     // 33,554,432 fu
    unsigned short* Gw   = (unsigned short*)(ws);                     // alias
    unsigned short* At   = (unsigned short*)(ws + 33554432);          // 16,777,216 fu
    float*          h    = ws + 50331648;                             //  2,097,152 fu
    unsigned short* h_bf = (unsigned short*)(ws + 52428800);          //  1,048,576 fu
    unsigned short* x_bf = (unsigned short*)(ws + 53477376);          //    262,144 fu
    unsigned short* u_bf = (unsigned short*)(ws + 53739520);          //     32,768 fu
    unsigned short* Wc1t = (unsigned short*)(ws + 53772288);          //    524,288 fu
    unsigned short* Wqt  = (unsigned short*)(ws + 54296576);          //    131,072 fu
    unsigned short* Wkt  = (unsigned short*)(ws + 54427648);
    unsigned short* Wvt  = (unsigned short*)(ws + 54558720);
    unsigned short* Wot  = (unsigned short*)(ws + 54689792);
    unsigned short* Wfpt = (unsigned short*)(ws + 54820864);          //     16,384 fu
    unsigned short* Wfot = (unsigned short*)(ws + 54837248);          //     16,384 fu
    float*          xa   = ws + 54853632;                             //     65,536 fu
    unsigned short* q_bf = (unsigned short*)(ws + 54919168);          //    262,144 fu
    unsigned short* k_bf = (unsigned short*)(ws + 55181312);
    unsigned short* vT   = (unsigned short*)(ws + 55443456);
    float*          sc   = ws + 55705600;                             //  4,194,304 fu
    unsigned short* at_bf= (unsigned short*)(ws + 59899904);          //  2,097,152 fu
    float*          av   = ws + 61997056;                             //    524,288 fu
    unsigned short* ctx  = (unsigned short*)(ws + 62521344);          //    262,144 fu
    unsigned short* upT2 = (unsigned short*)(ws + 62783488);
    unsigned short* ut_bf= (unsigned short*)(ws + 63045632);
    float* xout = (float*)d_out;
    float* uout = xout + 524288;

    const dim3 blk(256);

    // --- conversions ---
    tconv_k<<<dim3(32, 8), blk, 0, stream>>>(Wc1, Wc1t, 512, 2048);
    tconv_k<<<dim3(8, 8), blk, 0, stream>>>(Wq, Wqt, 512, 512);
    tconv_k<<<dim3(8, 8), blk, 0, stream>>>(Wk, Wkt, 512, 512);
    tconv_k<<<dim3(8, 8), blk, 0, stream>>>(Wv, Wvt, 512, 512);
    tconv_k<<<dim3(8, 8), blk, 0, stream>>>(Wo, Wot, 512, 512);
    tconv_k<<<dim3(8, 1), blk, 0, stream>>>(Wfp, Wfpt, 64, 512);
    tconv_k<<<dim3(1, 8), blk, 0, stream>>>(Wfo, Wfot, 512, 64);
    wc2p_k<<<dim3(512, 32), blk, 0, stream>>>(Wc2, Wc2p);
    f2bf_k<<<dim3(2048), blk, 0, stream>>>(x, x_bf, 524288);
    f2bf_k<<<dim3(256), blk, 0, stream>>>(u, u_bf, 65536);

    // --- attention (bf16 MFMA) ---
    mgemm_k<128,3><<<dim3(4, 8, 1), blk, 0, stream>>>(
        x_bf, Wqt, bq, nullptr, nullptr, q_bf, 512, 512, 512, 512,
        1, 0,0,0,0,0,0, 1.0f);
    mgemm_k<128,3><<<dim3(4, 8, 1), blk, 0, stream>>>(
        x_bf, Wkt, bk, nullptr, nullptr, k_bf, 512, 512, 512, 512,
        1, 0,0,0,0,0,0, 1.0f);
    mgemm_k<128,5><<<dim3(4, 8, 1), blk, 0, stream>>>(
        x_bf, Wvt, bv, nullptr, nullptr, vT, 512, 512, 512, 512,
        1, 0,0,0,0,0,0, 1.0f);
    // scores = q.k^T/8, batched (b,h)
    mgemm_k<128,0><<<dim3(4, 4, 16), blk, 0, stream>>>(
        q_bf, k_bf, nullptr, nullptr, sc, nullptr, 64, 512, 512, 512,
        8, 262144,64, 262144,64, 2097152,262144, 0.125f);
    softmax_k<<<dim3(BB * HH * SS), blk, 0, stream>>>(sc, at_bf);
    aavg_k<<<dim3(2048), blk, 0, stream>>>(sc, av);
    // ctx = attn @ v, batched (b,h)
    mgemm_k<64,3><<<dim3(1, 4, 16), blk, 0, stream>>>(
        at_bf, vT, nullptr, nullptr, nullptr, ctx, 512, 512, 512, 512,
        8, 2097152,262144, 262144,32768, 262144,64, 1.0f);
    // x_out = x + ctx @ Wo + bo
    mgemm_k<128,4><<<dim3(4, 8, 1), blk, 0, stream>>>(
        ctx, Wot, bo, x, xout, nullptr, 512, 512, 512, 512,
        1, 0,0,0,0,0,0, 1.0f);

    // --- connection network ---
    mgemm_k<128,1><<<dim3(16, 8, 1), blk, 0, stream>>>(
        x_bf, Wc1t, bc1, nullptr, h, nullptr, 512, 512, 512, 2048,
        1, 0,0,0,0,0,0, 1.0f);
    lnbf_k<<<dim3(1024), blk, 0, stream>>>(h, gln, bln, h_bf);
    mgemm_k<128,2><<<dim3(256, 8, 1), blk, 0, stream>>>(
        h_bf, Wc2p, bc2, nullptr, nullptr, At, 2048, 2048, 2048, 32768,
        1, 0,0,0,0,0,0, 1.0f);
    xa_k<<<dim3(1024), blk, 0, stream>>>(x, At, xa);
    liegamma_k<<<dim3(4, 512, 2), blk, 0, stream>>>(x_bf, At, xa, av, Gw);

    // --- fiber transport ---
    mgemm_k<128,6><<<dim3(4, 8, 1), blk, 0, stream>>>(
        u_bf, Wfpt, bfp, nullptr, nullptr, upT2, 64, 64, 64, 512,
        1, 0,0,0,0,0,0, 1.0f);
    // ut[b,i,k*64+c] = Gw[b,k] @ upT2[b]^T, batched (b,k)
    mgemm_k<64,3><<<dim3(1, 4, 16), blk, 0, stream>>>(
        Gw, upT2, nullptr, nullptr, nullptr, ut_bf, 4096, 4096, 4096, 512,
        8, 16777216,2097152, 262144,0, 262144,64, 1.0f);
    // u_out = u + ut @ Wfo + bfo
    mgemm_k<64,4><<<dim3(1, 8, 1), blk, 0, stream>>>(
        ut_bf, Wfot, bfo, u, uout, nullptr, 512, 512, 512, 64,
        1, 0,0,0,0,0,0, 1.0f);
}